// Round 3
// baseline (230.866 us; speedup 1.0000x reference)
//
#include <hip/hip_runtime.h>
#include <math.h>

#define DX 192
#define DY 192
#define DZ 128
#define DB 4
#define DXY (DX*DY)          // 36864
#define NTOT (DB*DZ*DXY)     // 18874368
#define XV (DX/4)            // 48 vec4 groups per row
#define NCOL (DB*DZ*XV)      // 24576 columns (b,z,xv4)
#define SEG 12               // y rows per thread
#define NSEG (DY/SEG)        // 16 segments per column

// ws layout (doubles): [0..12] sum(di*dt), [13..25] sum(dt*dt), [26] bce sum

__device__ inline float wred(float v) {
    #pragma unroll
    for (int o = 32; o > 0; o >>= 1) v += __shfl_down(v, o, 64);
    return v;
}

__device__ inline float4 ld4(const float* p) { return *(const float4*)p; }

// --- term macros -----------------------------------------------------------
#define TN(k, A1, A0, D1, D0) do { float di_=(A1)-(A0); float dt_=(D1)-(D0); \
    sk[k] += di_*dt_; rk[k] += dt_*dt_; } while(0)
#define TM(k, A1, A0, D1, D0) do { float di_=(A1)-(A0); float dt_=(D1)-(D0); \
    float dm_=fx3*dt_; sk[k] += di_*dm_; rk[k] += dt_*dm_; } while(0)
#define BCEACC(A0, D0) do { bces += (D0)*__logf(A0) + (1.0f-(D0))*__logf(1.0f-(A0)); } while(0)

// corners (z,y,x): a0=(0,0,0) a1=(0,0,1) a2=(0,1,0) a3=(0,1,1)
//                  a4=(1,0,0) a5=(1,0,1) a6=(1,1,0) a7=(1,1,1)
// offsets -> pairs: k0:(4,0) k1:(2,0) k2:(1,0) k3:(6,0) k4:(4,2) k5:(3,0)
//                   k6:(2,1) k7:(4,1) k8:(5,0) k9:(4,3) k10:(6,1) k11:(7,0) k12:(5,2)

#define ELEM_FULL(a0,a1,a2,a3,a4,a5,a6,a7, d0,d1,d2,d3,d4,d5,d6,d7) do { \
    TN(0,a4,a0,d4,d0); TN(1,a2,a0,d2,d0); TN(2,a1,a0,d1,d0); TN(3,a6,a0,d6,d0); \
    TN(4,a4,a2,d4,d2); TN(5,a3,a0,d3,d0); TN(6,a2,a1,d2,d1); TN(7,a4,a1,d4,d1); \
    TN(8,a5,a0,d5,d0); TN(9,a4,a3,d4,d3); TN(10,a6,a1,d6,d1); TN(11,a7,a0,d7,d0); \
    TN(12,a5,a2,d5,d2); BCEACC(a0,d0); } while(0)

#define ELEM_FX(a0,a1,a2,a3,a4,a5,a6,a7, d0,d1,d2,d3,d4,d5,d6,d7) do { \
    TN(0,a4,a0,d4,d0); TN(1,a2,a0,d2,d0); TM(2,a1,a0,d1,d0); TN(3,a6,a0,d6,d0); \
    TN(4,a4,a2,d4,d2); TM(5,a3,a0,d3,d0); TM(6,a2,a1,d2,d1); TM(7,a4,a1,d4,d1); \
    TM(8,a5,a0,d5,d0); TM(9,a4,a3,d4,d3); TM(10,a6,a1,d6,d1); TM(11,a7,a0,d7,d0); \
    TM(12,a5,a2,d5,d2); BCEACC(a0,d0); } while(0)

// y=191 peel (z<127): only dy==0 offsets survive: k0,k2,k7,k8
#define PEL_FULL(a0,a1,a4,a5, d0,d1,d4,d5) do { \
    TN(0,a4,a0,d4,d0); TN(2,a1,a0,d1,d0); TN(7,a4,a1,d4,d1); TN(8,a5,a0,d5,d0); \
    BCEACC(a0,d0); } while(0)
#define PEL_FX(a0,a1,a4,a5, d0,d1,d4,d5) do { \
    TN(0,a4,a0,d4,d0); TM(2,a1,a0,d1,d0); TM(7,a4,a1,d4,d1); TM(8,a5,a0,d5,d0); \
    BCEACC(a0,d0); } while(0)

// z=127 body: only dz==0 offsets survive: k1,k2,k5,k6
#define ZEL_FULL(a0,a1,a2,a3, d0,d1,d2,d3) do { \
    TN(1,a2,a0,d2,d0); TN(2,a1,a0,d1,d0); TN(5,a3,a0,d3,d0); TN(6,a2,a1,d2,d1); \
    BCEACC(a0,d0); } while(0)
#define ZEL_FX(a0,a1,a2,a3, d0,d1,d2,d3) do { \
    TN(1,a2,a0,d2,d0); TM(2,a1,a0,d1,d0); TM(5,a3,a0,d3,d0); TM(6,a2,a1,d2,d1); \
    BCEACC(a0,d0); } while(0)

// z=127, y=191 peel: only k2
#define ZPEL_FULL(a0,a1, d0,d1) do { TN(2,a1,a0,d1,d0); BCEACC(a0,d0); } while(0)
#define ZPEL_FX(a0,a1, d0,d1)   do { TM(2,a1,a0,d1,d0); BCEACC(a0,d0); } while(0)

__global__ __launch_bounds__(256) void gc3d_main(const float* __restrict__ inp,
                                                 const float* __restrict__ tgt,
                                                 double* __restrict__ acc) {
    float sk[13] = {0,0,0,0,0,0,0,0,0,0,0,0,0};
    float rk[13] = {0,0,0,0,0,0,0,0,0,0,0,0,0};
    float bces = 0.f;

    int c   = blockIdx.x * 256 + threadIdx.x;   // [0, 24576)
    int s   = blockIdx.y;                       // [0, 16)
    int xv4 = c % XV;
    int zb  = c / XV;                           // b*DZ + z, [0, 512)
    int z   = zb & (DZ - 1);
    int y0  = s * SEG;
    bool xlast = (xv4 == XV - 1);
    int   xe   = xlast ? 3 : 4;
    float fx3  = xlast ? 0.f : 1.f;
    bool lastseg = (s == NSEG - 1);
    int  nfull   = SEG - (lastseg ? 1 : 0);     // 11 or 12 computed rows

    int base = (zb * DY + y0) * DX + xv4 * 4;
    const float* ip = inp + base;
    const float* tp = tgt + base;

    if (z != DZ - 1) {
        // ---------- z-interior path, distance-2 software pipeline ----------
        // sets: A=row y (resident), B=row y+1 (resident), C=row y+2 (arriving),
        //       D=row y+3 (issued in-loop). Load of row r issued >=2 iters before use.
        const float* ipz = ip + DXY;
        const float* tpz = tp + DXY;

        float4 Ai0=ld4(ip),      Ai1=ld4(ipz),      At0=ld4(tp),      At1=ld4(tpz);
        float  Aie=ip[xe],       Aiz=ipz[xe],       Ate=tp[xe],       Atz=tpz[xe];
        float4 Bi0=ld4(ip+DX),   Bi1=ld4(ipz+DX),   Bt0=ld4(tp+DX),   Bt1=ld4(tpz+DX);
        float  Bie=ip[DX+xe],    Biz=ipz[DX+xe],    Bte=tp[DX+xe],    Btz=tpz[DX+xe];
        float4 Ci0=ld4(ip+2*DX), Ci1=ld4(ipz+2*DX), Ct0=ld4(tp+2*DX), Ct1=ld4(tpz+2*DX);
        float  Cie=ip[2*DX+xe],  Ciz=ipz[2*DX+xe],  Cte=tp[2*DX+xe],  Ctz=tpz[2*DX+xe];
        float4 Di0=Ci0, Di1=Ci1, Dt0=Ct0, Dt1=Ct1;
        float  Die=Cie, Diz=Ciz, Dte=Cte, Dtz=Ctz;

        #pragma unroll 2
        for (int it = 0; it < nfull; ++it) {
            if (it + 3 <= nfull) {   // block-uniform guard; max issued row = y0+nfull <= 191
                Di0=ld4(ip+3*DX);  Di1=ld4(ipz+3*DX);
                Dt0=ld4(tp+3*DX);  Dt1=ld4(tpz+3*DX);
                Die=ip[3*DX+xe];   Diz=ipz[3*DX+xe];
                Dte=tp[3*DX+xe];   Dtz=tpz[3*DX+xe];
            }

            // compute rows y (A) and y+1 (B)
            ELEM_FULL(Ai0.x,Ai0.y, Bi0.x,Bi0.y, Ai1.x,Ai1.y, Bi1.x,Bi1.y,
                      At0.x,At0.y, Bt0.x,Bt0.y, At1.x,At1.y, Bt1.x,Bt1.y);
            ELEM_FULL(Ai0.y,Ai0.z, Bi0.y,Bi0.z, Ai1.y,Ai1.z, Bi1.y,Bi1.z,
                      At0.y,At0.z, Bt0.y,Bt0.z, At1.y,At1.z, Bt1.y,Bt1.z);
            ELEM_FULL(Ai0.z,Ai0.w, Bi0.z,Bi0.w, Ai1.z,Ai1.w, Bi1.z,Bi1.w,
                      At0.z,At0.w, Bt0.z,Bt0.w, At1.z,At1.w, Bt1.z,Bt1.w);
            ELEM_FX  (Ai0.w,Aie,  Bi0.w,Bie,  Ai1.w,Aiz,  Bi1.w,Biz,
                      At0.w,Ate,  Bt0.w,Bte,  At1.w,Atz,  Bt1.w,Btz);

            // rotate A<-B<-C<-D
            Ai0=Bi0; Ai1=Bi1; At0=Bt0; At1=Bt1; Aie=Bie; Aiz=Biz; Ate=Bte; Atz=Btz;
            Bi0=Ci0; Bi1=Ci1; Bt0=Ct0; Bt1=Ct1; Bie=Cie; Biz=Ciz; Bte=Cte; Btz=Ctz;
            Ci0=Di0; Ci1=Di1; Ct0=Dt0; Ct1=Dt1; Cie=Die; Ciz=Diz; Cte=Dte; Ctz=Dtz;
            ip += DX; ipz += DX; tp += DX; tpz += DX;
        }
        if (lastseg) {
            // after the final rotate, A holds row y=191
            PEL_FULL(Ai0.x,Ai0.y, Ai1.x,Ai1.y, At0.x,At0.y, At1.x,At1.y);
            PEL_FULL(Ai0.y,Ai0.z, Ai1.y,Ai1.z, At0.y,At0.z, At1.y,At1.z);
            PEL_FULL(Ai0.z,Ai0.w, Ai1.z,Ai1.w, At0.z,At0.w, At1.z,At1.w);
            PEL_FX  (Ai0.w,Aie,  Ai1.w,Aiz,  At0.w,Ate,  At1.w,Atz);
        }
    } else {
        // ---------- z = 127 path, distance-2 pipeline (half-size sets) ----------
        float4 Ai0=ld4(ip),      At0=ld4(tp);
        float  Aie=ip[xe],       Ate=tp[xe];
        float4 Bi0=ld4(ip+DX),   Bt0=ld4(tp+DX);
        float  Bie=ip[DX+xe],    Bte=tp[DX+xe];
        float4 Ci0=ld4(ip+2*DX), Ct0=ld4(tp+2*DX);
        float  Cie=ip[2*DX+xe],  Cte=tp[2*DX+xe];
        float4 Di0=Ci0, Dt0=Ct0;
        float  Die=Cie, Dte=Cte;

        #pragma unroll 2
        for (int it = 0; it < nfull; ++it) {
            if (it + 3 <= nfull) {
                Di0=ld4(ip+3*DX);  Dt0=ld4(tp+3*DX);
                Die=ip[3*DX+xe];   Dte=tp[3*DX+xe];
            }

            ZEL_FULL(Ai0.x,Ai0.y, Bi0.x,Bi0.y, At0.x,At0.y, Bt0.x,Bt0.y);
            ZEL_FULL(Ai0.y,Ai0.z, Bi0.y,Bi0.z, At0.y,At0.z, Bt0.y,Bt0.z);
            ZEL_FULL(Ai0.z,Ai0.w, Bi0.z,Bi0.w, At0.z,At0.w, Bt0.z,Bt0.w);
            ZEL_FX  (Ai0.w,Aie,  Bi0.w,Bie,  At0.w,Ate,  Bt0.w,Bte);

            Ai0=Bi0; At0=Bt0; Aie=Bie; Ate=Bte;
            Bi0=Ci0; Bt0=Ct0; Bie=Cie; Bte=Cte;
            Ci0=Di0; Ct0=Dt0; Cie=Die; Cte=Dte;
            ip += DX; tp += DX;
        }
        if (lastseg) {
            ZPEL_FULL(Ai0.x,Ai0.y, At0.x,At0.y);
            ZPEL_FULL(Ai0.y,Ai0.z, At0.y,At0.z);
            ZPEL_FULL(Ai0.z,Ai0.w, At0.z,At0.w);
            ZPEL_FX  (Ai0.w,Aie,  At0.w,Ate);
        }
    }

    // block reduction: wave shuffle -> LDS -> 27 double atomics
    float vals[27];
    #pragma unroll
    for (int q = 0; q < 13; q++) { vals[q] = sk[q]; vals[13 + q] = rk[q]; }
    vals[26] = bces;
    #pragma unroll
    for (int q = 0; q < 27; q++) vals[q] = wred(vals[q]);

    __shared__ float red[4][27];
    int lane = threadIdx.x & 63;
    int wave = threadIdx.x >> 6;
    if (lane == 0) {
        #pragma unroll
        for (int q = 0; q < 27; q++) red[wave][q] = vals[q];
    }
    __syncthreads();
    if (threadIdx.x < 27) {
        float t = red[0][threadIdx.x] + red[1][threadIdx.x]
                + red[2][threadIdx.x] + red[3][threadIdx.x];
        atomicAdd(&acc[threadIdx.x], (double)t);
    }
}

__global__ void gc3d_final(const double* __restrict__ acc, float* __restrict__ out) {
    if (threadIdx.x == 0 && blockIdx.x == 0) {
        double s = 0.0;
        #pragma unroll
        for (int k = 0; k < 13; k++) s += acc[k] / (acc[13 + k] + 1e-5);
        double bce = -acc[26] / (double)NTOT;
        out[0] = (float)(bce + 1.0 - s / 13.0);
    }
}

extern "C" void kernel_launch(void* const* d_in, const int* in_sizes, int n_in,
                              void* d_out, int out_size, void* d_ws, size_t ws_size,
                              hipStream_t stream) {
    const float* inp = (const float*)d_in[0];
    const float* tgt = (const float*)d_in[1];
    double* acc = (double*)d_ws;

    hipMemsetAsync(d_ws, 0, 27 * sizeof(double), stream);
    dim3 grid(NCOL / 256, NSEG);
    gc3d_main<<<grid, 256, 0, stream>>>(inp, tgt, acc);
    gc3d_final<<<1, 64, 0, stream>>>(acc, (float*)d_out);
}